// Round 6
// baseline (392.726 us; speedup 1.0000x reference)
//
#include <hip/hip_runtime.h>
#include <math.h>

#define Bn 512
#define Tn 1024
#define Nn 64
#define LOG2E_F 1.44269504088896340736f
#define LN2_F   0.69314718055994530942f

typedef float v2f __attribute__((ext_vector_type(2)));
typedef float v4f __attribute__((ext_vector_type(4)));

__device__ __forceinline__ float wave_max(float v) {
    #pragma unroll
    for (int o = 32; o > 0; o >>= 1) v = fmaxf(v, __shfl_xor(v, o));
    return v;
}
__device__ __forceinline__ float wave_sum(float v) {
    #pragma unroll
    for (int o = 32; o > 0; o >>= 1) v += __shfl_xor(v, o);
    return v;
}

// ---------------------------------------------------------------------------
// Kernel 1: unary + binary scores -> out[b]
// ---------------------------------------------------------------------------
__global__ __launch_bounds__(256) void crf_scores(
    const float* __restrict__ inputs, const float* __restrict__ trans,
    const int* __restrict__ tags, const int* __restrict__ lens,
    float* __restrict__ out)
{
    const int b = blockIdx.x;
    const int L = lens[b];
    const int* tagb = tags + b * Tn;
    const float* inb = inputs + (size_t)b * Tn * Nn;

    float acc = 0.f;
    for (int t = threadIdx.x; t < L; t += 256) {
        int tg = tagb[t];
        acc += inb[t * Nn + tg];
        if (t >= 1) acc += trans[tagb[t - 1] * Nn + tg];
    }
    acc = wave_sum(acc);
    __shared__ float red[4];
    if ((threadIdx.x & 63) == 0) red[threadIdx.x >> 6] = acc;
    __syncthreads();
    if (threadIdx.x == 0) out[b] = (red[0] + red[1]) + (red[2] + red[3]);
}

// ---------------------------------------------------------------------------
// Kernel 2: forward/backward halves of the linear recursion in exp-space.
//   fwd: q'_j = e^{x_t,j}/64 * sum_i q_i E[i][j]     (lane j holds col j of E)
//   bwd: q'_j = sum_i (e^{x_t}/64 * q)_i E[j][i]     (lane j holds row j of E)
// Broadcast via barrier-free LDS: single wave per block => the DS pipe's
// per-wave in-order execution makes ds_write -> ds_read RAW-safe with NO
// __syncthreads (so no vmcnt(0) drain: that was R2's 2000-cyc/step killer).
// R5's readlane variant stalled ~740 cyc/step on the v_readlane->SGPR->v_fma
// wait-state chain; broadcast ds_read_b128 (same-address = conflict-free)
// feeds packed v_pk_fma_f32 instead.
// ---------------------------------------------------------------------------
template <bool FULL>
__global__ __launch_bounds__(64, 1) void crf_fwdbwd(
    const float* __restrict__ inputs, const float* __restrict__ trans,
    const int* __restrict__ lens, float* __restrict__ ws,
    float* __restrict__ out)
{
    const int j = threadIdx.x;
    const bool bwd = (!FULL) && (blockIdx.x >= Bn);
    const int b = bwd ? (blockIdx.x - Bn) : blockIdx.x;
    const int L = lens[b];
    const float* inb = inputs + (size_t)b * Tn * Nn;

    __shared__ float trsh[64 * 65];
    __shared__ __align__(16) float qsh[64];

    // E2: 32 float2 per lane (the 64 E-column/row entries as packed pairs)
    v2f E2[32];
    if (!bwd) {
        #pragma unroll
        for (int i = 0; i < 32; ++i) {
            E2[i].x = exp2f(trans[(2 * i) * 64 + j] * LOG2E_F);
            E2[i].y = exp2f(trans[(2 * i + 1) * 64 + j] * LOG2E_F);
        }
    } else {
        #pragma unroll
        for (int i = 0; i < 64; ++i) trsh[i * 65 + j] = trans[i * 64 + j];
        __syncthreads();
        #pragma unroll
        for (int i = 0; i < 32; ++i) {
            E2[i].x = exp2f(trsh[j * 65 + 2 * i] * LOG2E_F);
            E2[i].y = exp2f(trsh[j * 65 + 2 * i + 1] * LOG2E_F);
        }
    }

    // s_j = sum_i v_i * E[i]; v broadcast through LDS, no barrier (1 wave).
    auto step_dot = [&](float vb) -> float {
        qsh[j] = vb;                               // ds_write_b32 (stride-1)
        __builtin_amdgcn_wave_barrier();
        asm volatile("" ::: "memory");             // don't cache qsh lanes
        v2f a0 = {0.f, 0.f}, a1 = {0.f, 0.f}, a2 = {0.f, 0.f}, a3 = {0.f, 0.f};
        #pragma unroll
        for (int i = 0; i < 64; i += 8) {
            v4f p = *(const v4f*)(qsh + i);        // broadcast ds_read_b128
            v4f r = *(const v4f*)(qsh + i + 4);
            v2f plo = {p.x, p.y}, phi = {p.z, p.w};
            v2f rlo = {r.x, r.y}, rhi = {r.z, r.w};
            a0 = plo * E2[i / 2]     + a0;         // contract -> v_pk_fma_f32
            a1 = phi * E2[i / 2 + 1] + a1;
            a2 = rlo * E2[i / 2 + 2] + a2;
            a3 = rhi * E2[i / 2 + 3] + a3;
        }
        v2f aa = (a0 + a1) + (a2 + a3);
        return aa.x + aa.y;
    };

    float q, base;
    int t0, dir, n;
    const int tf = L >> 1;           // forward covers t in [1,tf], backward (tf, L-1]
    if (!bwd) {
        float x0 = inb[j];
        float m = wave_max(x0);
        q = exp2f((x0 - m) * LOG2E_F);
        base = m;
        t0 = 1; dir = 1;
        n = FULL ? (L - 1) : tf;
    } else {
        q = 1.f; base = 0.f;
        t0 = L - 1; dir = -1;
        n = (L - 1) - tf;
    }

    // 4-deep register prefetch pipeline for x rows
    float xp[4];
    #pragma unroll
    for (int d = 0; d < 4; ++d) xp[d] = (d < n) ? inb[(t0 + d * dir) * Nn + j] : 0.f;

    int t = t0;
    float ex = exp2f(fmaf(xp[0], LOG2E_F, -6.0f));  // e^x / 64, one step ahead

#define STEP(BWDV, kk) do {                                        \
    float _xnew = 0.f;                                             \
    if ((kk) + 4 < n) _xnew = inb[(t + 4 * dir) * Nn + j];         \
    float _s;                                                      \
    if (BWDV) { float _v = ex * q; _s = step_dot(_v); }            \
    else      { _s = step_dot(q); }                                \
    xp[0] = xp[1]; xp[1] = xp[2]; xp[2] = xp[3]; xp[3] = _xnew;    \
    float _exn = exp2f(fmaf(xp[0], LOG2E_F, -6.0f));               \
    q = (BWDV) ? _s : ex * _s;                                     \
    ex = _exn; t += dir;                                           \
} while (0)

#define RENORM() do {                                              \
    float _m = wave_max(q);                                        \
    q *= (1.0f / _m);                                              \
    base += __logf(_m);                                            \
} while (0)

    int k = 0;
    if (!bwd) {
        while (k + 8 <= n) {
            #pragma unroll
            for (int u = 0; u < 8; ++u) STEP(false, k + u);
            k += 8;
            RENORM();
        }
        while (k < n) { STEP(false, k); ++k; }
    } else {
        while (k + 8 <= n) {
            #pragma unroll
            for (int u = 0; u < 8; ++u) STEP(true, k + u);
            k += 8;
            RENORM();
        }
        while (k < n) { STEP(true, k); ++k; }
    }

    // final renorm + account for the per-step 1/64 scaling
    {
        float m = wave_max(q);
        q *= (1.0f / m);
        base += __logf(m) + LN2_F * 6.0f * (float)n;
    }

    if (FULL) {
        float ssum = wave_sum(q);
        if (j == 0) out[b] -= (base + __logf(ssum));
    } else {
        float* fvec = ws;
        float* gvec = ws + Bn * 64;
        float* fb   = ws + 2 * Bn * 64;
        float* gb   = fb + Bn;
        if (!bwd) { fvec[b * 64 + j] = q; if (j == 0) fb[b] = base; }
        else      { gvec[b * 64 + j] = q; if (j == 0) gb[b] = base; }
    }
#undef STEP
#undef RENORM
}

// ---------------------------------------------------------------------------
// Kernel 3: combine halves: logZ = log(f . g) + fbase + gbase; out[b] -= logZ
// ---------------------------------------------------------------------------
__global__ __launch_bounds__(64, 1) void crf_combine(
    const float* __restrict__ ws, float* __restrict__ out)
{
    const int b = blockIdx.x;
    const int j = threadIdx.x;
    const float* fvec = ws;
    const float* gvec = ws + Bn * 64;
    const float* fb   = ws + 2 * Bn * 64;
    const float* gb   = fb + Bn;

    float p = wave_sum(fvec[b * 64 + j] * gvec[b * 64 + j]);
    if (j == 0) out[b] -= (__logf(p) + fb[b] + gb[b]);
}

extern "C" void kernel_launch(void* const* d_in, const int* in_sizes, int n_in,
                              void* d_out, int out_size, void* d_ws, size_t ws_size,
                              hipStream_t stream) {
    const float* inputs = (const float*)d_in[0];
    const float* trans  = (const float*)d_in[1];
    const int*   tags   = (const int*)d_in[2];
    const int*   lens   = (const int*)d_in[3];
    float* out = (float*)d_out;
    float* ws  = (float*)d_ws;

    crf_scores<<<Bn, 256, 0, stream>>>(inputs, trans, tags, lens, out);

    const size_t need = (size_t)(2 * Bn * 64 + 2 * Bn) * sizeof(float);
    if (ws_size >= need) {
        crf_fwdbwd<false><<<2 * Bn, 64, 0, stream>>>(inputs, trans, lens, ws, out);
        crf_combine<<<Bn, 64, 0, stream>>>(ws, out);
    } else {
        // workspace too small: single-direction fallback (slower, no ws needed)
        crf_fwdbwd<true><<<Bn, 64, 0, stream>>>(inputs, trans, lens, ws, out);
    }
}